// Round 11
// baseline (80.348 us; speedup 1.0000x reference)
//
#include <hip/hip_runtime.h>
#include <cstddef>

#define NUM_TYPE 64
#define DD 256
#define NN 8192
#define GM16 576   // max type-aligned 16-row groups: 8192/16 + 64

typedef __bf16 bf16x8 __attribute__((ext_vector_type(8)));
typedef float f32x4 __attribute__((ext_vector_type(4)));

__device__ __forceinline__ bf16x8 cvt8(const float* p) {
  float4 v0 = *reinterpret_cast<const float4*>(p);
  float4 v1 = *reinterpret_cast<const float4*>(p + 4);
  bf16x8 h;
  h[0] = (__bf16)v0.x; h[1] = (__bf16)v0.y; h[2] = (__bf16)v0.z; h[3] = (__bf16)v0.w;
  h[4] = (__bf16)v1.x; h[5] = (__bf16)v1.y; h[6] = (__bf16)v1.z; h[7] = (__bf16)v1.w;
  return h;
}

__device__ __forceinline__ float tanh_fast(float x) {
  float xc = fminf(fmaxf(x, -15.f), 15.f);
  float e = __expf(2.f * xc);
  return (e - 1.f) / (e + 1.f);
}

// --- Kernel 1: perm + type-aligned 16-row group table --------------------
__global__ __launch_bounds__(1024) void build_perm16(
    const int* __restrict__ bi, int* __restrict__ type_off,
    int* __restrict__ perm, int* __restrict__ gtype, int* __restrict__ gfirst) {
  __shared__ int wcnt[16][NUM_TYPE];
  __shared__ int wbase[16][NUM_TYPE];
  __shared__ int base[NUM_TYPE];
  const int tid = threadIdx.x;
  const int w = tid >> 6;
  for (int i = tid; i < 16 * NUM_TYPE; i += 1024) ((int*)wcnt)[i] = 0;
  __syncthreads();
  int myv[8];
#pragma unroll
  for (int rnd = 0; rnd < 8; ++rnd) {
    int v = bi[rnd * 1024 + tid];
    myv[rnd] = v;
    atomicAdd(&wcnt[w][v], 1);
  }
  __syncthreads();
  if (tid < NUM_TYPE) {
    int s = 0;
#pragma unroll
    for (int ww = 0; ww < 16; ++ww) { wbase[ww][tid] = s; s += wcnt[ww][tid]; }
    base[tid] = s;                         // per-type count
  }
  __syncthreads();
  if (tid == 0) {
    int s = 0, ng = 0;
    for (int t = 0; t < NUM_TYPE; ++t) {
      int c = base[t];
      base[t] = s; type_off[t] = s;
      for (int j = 0; j < c; j += 16) { gtype[ng] = t; gfirst[ng] = s + j; ++ng; }
      s += c;
    }
    type_off[NUM_TYPE] = s;
    for (; ng < GM16; ++ng) gtype[ng] = -1;
  }
  __syncthreads();
  if (tid < NUM_TYPE) {
    int b = base[tid];
#pragma unroll
    for (int ww = 0; ww < 16; ++ww) wbase[ww][tid] += b;
  }
  __syncthreads();
#pragma unroll
  for (int rnd = 0; rnd < 8; ++rnd) {
    int v = myv[rnd];
    int p = atomicAdd(&wbase[w][v], 1);
    perm[p] = rnd * 1024 + tid;
  }
}

// --- Kernel 2: one 16x16 tile per wave, ~9k waves, no LDS/barriers -------
// block b: group g = b>>2 (16 perm rows, single type), quarter cq = b&3;
// wave wv handles cols [colg*16, colg*16+16), colg = cq*4+wv.
// 4 waves of a block share the same 16 A rows -> L1 reuse.
__global__ __launch_bounds__(256, 6) void gemm16(
    const float* __restrict__ desc,
    const float* __restrict__ layer1,
    const float* __restrict__ W,
    const float* __restrict__ bias,
    const int* __restrict__ type_off,
    const int* __restrict__ perm,
    const int* __restrict__ gtype,
    const int* __restrict__ gfirst,
    float* __restrict__ out) {
  const int b = blockIdx.x;
  const int g = b >> 2;
  const int cq = b & 3;
  const int t = gtype[g];
  if (t < 0) return;

  const int wv = threadIdx.x >> 6;
  const int lane = threadIdx.x & 63;
  const int l15 = lane & 15;
  const int lg = lane >> 4;
  const int colg = cq * 4 + wv;
  const int cn0 = colg * 16 + l15;

  const int first = gfirst[g];
  const int limit = type_off[t + 1];
  const int r = first + l15;
  const int s0 = (r < limit) ? perm[r] : -1;

  const float* a0 = desc + (size_t)(s0 < 0 ? 0 : s0) * DD + lg * 8;
  const float* bl = layer1 + ((size_t)t * DD + cn0) * DD + lg * 8;
  const float* bw = W + (size_t)cn0 * DD + lg * 8;
  const float bv = bias[cn0];

  f32x4 accL = {0.f, 0.f, 0.f, 0.f};
  f32x4 accW = {0.f, 0.f, 0.f, 0.f};
#pragma unroll
  for (int kc = 0; kc < 8; ++kc) {
    bf16x8 af = cvt8(a0 + kc * 32);
    bf16x8 bL = cvt8(bl + kc * 32);
    bf16x8 bW = cvt8(bw + kc * 32);
    accL = __builtin_amdgcn_mfma_f32_16x16x32_bf16(af, bL, accL, 0, 0, 0);
    accW = __builtin_amdgcn_mfma_f32_16x16x32_bf16(af, bW, accW, 0, 0, 0);
  }

  // epilogue: acc row = lg*4+i, col = l15; each store = 4 full 64B lines
#pragma unroll
  for (int i = 0; i < 4; ++i) {
    const int sv = __shfl(s0, lg * 4 + i, 64);
    if (sv >= 0)
      __builtin_nontemporal_store(tanh_fast(accL[i]) + accW[i] + bv,
                                  out + (size_t)sv * DD + cn0);
  }
}

extern "C" void kernel_launch(void* const* d_in, const int* in_sizes, int n_in,
                              void* d_out, int out_size, void* d_ws, size_t ws_size,
                              hipStream_t stream) {
  const int* bi       = (const int*)d_in[0];
  const float* desc   = (const float*)d_in[1];
  const float* layer1 = (const float*)d_in[2];
  const float* W      = (const float*)d_in[3];
  const float* bias   = (const float*)d_in[4];
  float* out = (float*)d_out;

  char* ws = (char*)d_ws;
  int* type_off = (int*)(ws);              // 65 ints   @ 0
  int* gtype    = (int*)(ws + 1024);       // 576 ints  @ 1 KB
  int* gfirst   = (int*)(ws + 4096);       // 576 ints  @ 4 KB
  int* perm     = (int*)(ws + 8192);       // 8192 ints @ 8 KB

  hipLaunchKernelGGL(build_perm16, dim3(1), dim3(1024), 0, stream,
                     bi, type_off, perm, gtype, gfirst);
  hipLaunchKernelGGL(gemm16, dim3(GM16 * 4), dim3(256), 0, stream,
                     desc, layer1, W, bias, type_off, perm, gtype, gfirst, out);
}

// Round 12
// 38.579 us; speedup vs baseline: 2.0827x; 2.0827x over previous
//
#include <hip/hip_runtime.h>
#include <cstddef>

#define NUM_TYPE 64
#define DD 256
#define NN 8192
#define GM32 320      // max type-aligned 32-row groups: 8192/32 + 64
#define LSTR 40       // LDS row stride (bf16 elems), +8 pad

typedef __bf16 bf16x8 __attribute__((ext_vector_type(8)));
typedef __bf16 bf16x4 __attribute__((ext_vector_type(4)));
typedef float f32x4 __attribute__((ext_vector_type(4)));

__device__ __forceinline__ bf16x4 cvt4(float4 v) {
  bf16x4 h;
  h[0] = (__bf16)v.x; h[1] = (__bf16)v.y; h[2] = (__bf16)v.z; h[3] = (__bf16)v.w;
  return h;
}

__device__ __forceinline__ float tanh_fast(float x) {
  float xc = fminf(fmaxf(x, -15.f), 15.f);
  float e = __expf(2.f * xc);
  return (e - 1.f) / (e + 1.f);
}

// --- Kernel 1: perm + type-aligned 32-row group table --------------------
__global__ __launch_bounds__(1024) void build_perm32(
    const int* __restrict__ bi, int* __restrict__ type_off,
    int* __restrict__ perm, int* __restrict__ gtype, int* __restrict__ gfirst) {
  __shared__ int wcnt[16][NUM_TYPE];
  __shared__ int wbase[16][NUM_TYPE];
  __shared__ int base[NUM_TYPE];
  const int tid = threadIdx.x;
  const int w = tid >> 6;
  for (int i = tid; i < 16 * NUM_TYPE; i += 1024) ((int*)wcnt)[i] = 0;
  __syncthreads();
  int myv[8];
#pragma unroll
  for (int rnd = 0; rnd < 8; ++rnd) {
    int v = bi[rnd * 1024 + tid];
    myv[rnd] = v;
    atomicAdd(&wcnt[w][v], 1);
  }
  __syncthreads();
  if (tid < NUM_TYPE) {
    int s = 0;
#pragma unroll
    for (int ww = 0; ww < 16; ++ww) { wbase[ww][tid] = s; s += wcnt[ww][tid]; }
    base[tid] = s;                         // per-type count
  }
  __syncthreads();
  if (tid == 0) {
    int s = 0, ng = 0;
    for (int t = 0; t < NUM_TYPE; ++t) {
      int c = base[t];
      base[t] = s; type_off[t] = s;
      for (int j = 0; j < c; j += 32) { gtype[ng] = t; gfirst[ng] = s + j; ++ng; }
      s += c;
    }
    type_off[NUM_TYPE] = s;
    for (; ng < GM32; ++ng) gtype[ng] = -1;
  }
  __syncthreads();
  if (tid < NUM_TYPE) {
    int b = base[tid];
#pragma unroll
    for (int ww = 0; ww < 16; ++ww) wbase[ww][tid] += b;
  }
  __syncthreads();
#pragma unroll
  for (int rnd = 0; rnd < 8; ++rnd) {
    int v = myv[rnd];
    int p = atomicAdd(&wbase[w][v], 1);
    perm[p] = rnd * 1024 + tid;
  }
}

// --- Kernel 2: blocked GEMM 32x64 tile, BK=32 double-buffered LDS --------
// grid 1280 = 8 XCDs x 160; dispatch d -> logical l=(d&7)*160+d>>3 so each
// XCD owns a contiguous run of (group, colblock) pairs -> L2-local panels.
// 4 waves: wave w -> rows wr*16..+16, cols wc*32..+32 of the 32x64 tile.
__global__ __launch_bounds__(256) void gemm_tile(
    const float* __restrict__ desc,
    const float* __restrict__ layer1,
    const float* __restrict__ W,
    const float* __restrict__ bias,
    const int* __restrict__ type_off,
    const int* __restrict__ perm,
    const int* __restrict__ gtype,
    const int* __restrict__ gfirst,
    float* __restrict__ out) {
  const int d = blockIdx.x;
  const int l = (d & 7) * 160 + (d >> 3);
  const int g = l >> 2;
  const int cb = l & 3;
  const int t = gtype[g];
  if (t < 0) return;
  const int first = gfirst[g];
  const int limit = type_off[t + 1];

  const int tid = threadIdx.x;
  const int w = tid >> 6;
  const int lane = tid & 63;
  const int l15 = lane & 15;
  const int lg = lane >> 4;
  const int wr = w >> 1;
  const int wc = w & 1;

  __shared__ __bf16 At[2][32][LSTR];
  __shared__ __bf16 Bl[2][64][LSTR];
  __shared__ __bf16 Bw[2][64][LSTR];

  // staging geometry: 8 lanes x 16B cover one 128B row-segment (32 floats)
  const int srow = tid >> 3;             // 0..31
  const int seg = tid & 7;               // 0..7
  const int ar = first + srow;
  const int sA = (ar < limit) ? perm[ar] : -1;
  const float* aP   = desc + (size_t)(sA < 0 ? 0 : sA) * DD + seg * 4;
  const int gc0 = cb * 64 + srow;
  const float* blP0 = layer1 + ((size_t)t * DD + gc0) * DD + seg * 4;
  const float* blP1 = blP0 + (size_t)32 * DD;
  const float* bwP0 = W + (size_t)gc0 * DD + seg * 4;
  const float* bwP1 = bwP0 + (size_t)32 * DD;

#define STAGE(buf, kb)                                                        \
  {                                                                           \
    float4 va = make_float4(0.f, 0.f, 0.f, 0.f);                              \
    if (sA >= 0) va = *reinterpret_cast<const float4*>(aP + (kb));            \
    *reinterpret_cast<bf16x4*>(&At[buf][srow][seg * 4]) = cvt4(va);           \
    *reinterpret_cast<bf16x4*>(&Bl[buf][srow][seg * 4]) =                     \
        cvt4(*reinterpret_cast<const float4*>(blP0 + (kb)));                  \
    *reinterpret_cast<bf16x4*>(&Bl[buf][srow + 32][seg * 4]) =                \
        cvt4(*reinterpret_cast<const float4*>(blP1 + (kb)));                  \
    *reinterpret_cast<bf16x4*>(&Bw[buf][srow][seg * 4]) =                     \
        cvt4(*reinterpret_cast<const float4*>(bwP0 + (kb)));                  \
    *reinterpret_cast<bf16x4*>(&Bw[buf][srow + 32][seg * 4]) =                \
        cvt4(*reinterpret_cast<const float4*>(bwP1 + (kb)));                  \
  }

  STAGE(0, 0)
  __syncthreads();

  f32x4 accL[2] = {{0.f,0.f,0.f,0.f},{0.f,0.f,0.f,0.f}};
  f32x4 accW[2] = {{0.f,0.f,0.f,0.f},{0.f,0.f,0.f,0.f}};
  int buf = 0;
#pragma unroll
  for (int kc = 0; kc < 8; ++kc) {
    if (kc < 7) STAGE(buf ^ 1, (kc + 1) * 32)
    bf16x8 af = *reinterpret_cast<const bf16x8*>(&At[buf][wr * 16 + l15][lg * 8]);
    bf16x8 b0 = *reinterpret_cast<const bf16x8*>(&Bl[buf][wc * 32 + l15][lg * 8]);
    bf16x8 b1 = *reinterpret_cast<const bf16x8*>(&Bl[buf][wc * 32 + 16 + l15][lg * 8]);
    bf16x8 w0 = *reinterpret_cast<const bf16x8*>(&Bw[buf][wc * 32 + l15][lg * 8]);
    bf16x8 w1 = *reinterpret_cast<const bf16x8*>(&Bw[buf][wc * 32 + 16 + l15][lg * 8]);
    accL[0] = __builtin_amdgcn_mfma_f32_16x16x32_bf16(af, b0, accL[0], 0, 0, 0);
    accL[1] = __builtin_amdgcn_mfma_f32_16x16x32_bf16(af, b1, accL[1], 0, 0, 0);
    accW[0] = __builtin_amdgcn_mfma_f32_16x16x32_bf16(af, w0, accW[0], 0, 0, 0);
    accW[1] = __builtin_amdgcn_mfma_f32_16x16x32_bf16(af, w1, accW[1], 0, 0, 0);
    __syncthreads();
    buf ^= 1;
  }
#undef STAGE

  // epilogue: acc row = lg*4+i within wave's 16 rows, col = l15
  const int orow = first + wr * 16 + l15;
  const int sOut = (orow < limit) ? perm[orow] : -1;
#pragma unroll
  for (int n = 0; n < 2; ++n) {
    const int col = cb * 64 + wc * 32 + n * 16 + l15;
    const float bv = bias[col];
#pragma unroll
    for (int i = 0; i < 4; ++i) {
      const int sv = __shfl(sOut, lg * 4 + i, 64);
      if (sv >= 0)
        __builtin_nontemporal_store(tanh_fast(accL[n][i]) + accW[n][i] + bv,
                                    out + (size_t)sv * DD + col);
    }
  }
}

extern "C" void kernel_launch(void* const* d_in, const int* in_sizes, int n_in,
                              void* d_out, int out_size, void* d_ws, size_t ws_size,
                              hipStream_t stream) {
  const int* bi       = (const int*)d_in[0];
  const float* desc   = (const float*)d_in[1];
  const float* layer1 = (const float*)d_in[2];
  const float* W      = (const float*)d_in[3];
  const float* bias   = (const float*)d_in[4];
  float* out = (float*)d_out;

  char* ws = (char*)d_ws;
  int* type_off = (int*)(ws);              // 65 ints   @ 0
  int* gtype    = (int*)(ws + 1024);       // 320 ints  @ 1 KB
  int* gfirst   = (int*)(ws + 4096);       // 320 ints  @ 4 KB
  int* perm     = (int*)(ws + 8192);       // 8192 ints @ 8 KB

  hipLaunchKernelGGL(build_perm32, dim3(1), dim3(1024), 0, stream,
                     bi, type_off, perm, gtype, gfirst);
  hipLaunchKernelGGL(gemm_tile, dim3(GM32 * 4), dim3(256), 0, stream,
                     desc, layer1, W, bias, type_off, perm, gtype, gfirst, out);
}

// Round 13
// 26.267 us; speedup vs baseline: 3.0589x; 1.4688x over previous
//
#include <hip/hip_runtime.h>
#include <cstddef>

#define NUM_TYPE 64
#define DD 256
#define NN 8192
#define GM32 320      // max type-aligned 32-row groups: 8192/32 + 64
#define LSTR 40       // LDS row stride (bf16 elems), +8 pad

typedef __bf16 bf16x8 __attribute__((ext_vector_type(8)));
typedef __bf16 bf16x4 __attribute__((ext_vector_type(4)));
typedef float f32x4 __attribute__((ext_vector_type(4)));

__device__ __forceinline__ bf16x4 cvt4(float4 v) {
  bf16x4 h;
  h[0] = (__bf16)v.x; h[1] = (__bf16)v.y; h[2] = (__bf16)v.z; h[3] = (__bf16)v.w;
  return h;
}

__device__ __forceinline__ float tanh_fast(float x) {
  float xc = fminf(fmaxf(x, -15.f), 15.f);
  float e = __expf(2.f * xc);
  return (e - 1.f) / (e + 1.f);
}

// --- Kernel 1: perm + type-aligned 32-row group table (parallel emit) ----
__global__ __launch_bounds__(1024) void build_perm32(
    const int* __restrict__ bi, int* __restrict__ type_off,
    int* __restrict__ perm, int* __restrict__ gtype, int* __restrict__ gfirst) {
  __shared__ int wcnt[16][NUM_TYPE];
  __shared__ int wbase[16][NUM_TYPE];
  __shared__ int cnt[NUM_TYPE];
  __shared__ int tstart[NUM_TYPE];
  __shared__ int gbase[NUM_TYPE];
  __shared__ int totals[2];              // [0]=rows, [1]=groups
  const int tid = threadIdx.x;
  const int w = tid >> 6;
  for (int i = tid; i < 16 * NUM_TYPE; i += 1024) ((int*)wcnt)[i] = 0;
  __syncthreads();
  int myv[8];
#pragma unroll
  for (int rnd = 0; rnd < 8; ++rnd) {
    int v = bi[rnd * 1024 + tid];
    myv[rnd] = v;
    atomicAdd(&wcnt[w][v], 1);
  }
  __syncthreads();
  if (tid < NUM_TYPE) {
    int s = 0;
#pragma unroll
    for (int ww = 0; ww < 16; ++ww) { wbase[ww][tid] = s; s += wcnt[ww][tid]; }
    cnt[tid] = s;
  }
  __syncthreads();
  if (tid == 0) {                        // 64-iter serial scan in LDS (fast)
    int s = 0, p = 0;
    for (int t = 0; t < NUM_TYPE; ++t) {
      tstart[t] = s; gbase[t] = p;
      s += cnt[t];
      p += (cnt[t] + 31) >> 5;
    }
    totals[0] = s; totals[1] = p;
  }
  __syncthreads();
  // parallel table emit: one thread per type
  if (tid < NUM_TYPE) {
    const int c = cnt[tid];
    const int ngr = (c + 31) >> 5;
    const int g0 = gbase[tid];
    const int s0 = tstart[tid];
    for (int j = 0; j < ngr; ++j) { gtype[g0 + j] = tid; gfirst[g0 + j] = s0 + j * 32; }
    type_off[tid] = s0;
    int b = s0;
#pragma unroll
    for (int ww = 0; ww < 16; ++ww) wbase[ww][tid] += b;
  }
  if (tid == 0) type_off[NUM_TYPE] = totals[0];
  // parallel tail fill
  for (int g = totals[1] + tid; g < GM32; g += 1024) gtype[g] = -1;
  __syncthreads();
#pragma unroll
  for (int rnd = 0; rnd < 8; ++rnd) {
    int v = myv[rnd];
    int p = atomicAdd(&wbase[w][v], 1);
    perm[p] = rnd * 1024 + tid;
  }
}

// --- Kernel 2: blocked GEMM 32x64 tile, BK=32 double-buffered LDS --------
// (byte-identical to round 12 — validated)
__global__ __launch_bounds__(256) void gemm_tile(
    const float* __restrict__ desc,
    const float* __restrict__ layer1,
    const float* __restrict__ W,
    const float* __restrict__ bias,
    const int* __restrict__ type_off,
    const int* __restrict__ perm,
    const int* __restrict__ gtype,
    const int* __restrict__ gfirst,
    float* __restrict__ out) {
  const int d = blockIdx.x;
  const int l = (d & 7) * 160 + (d >> 3);
  const int g = l >> 2;
  const int cb = l & 3;
  const int t = gtype[g];
  if (t < 0) return;
  const int first = gfirst[g];
  const int limit = type_off[t + 1];

  const int tid = threadIdx.x;
  const int w = tid >> 6;
  const int lane = tid & 63;
  const int l15 = lane & 15;
  const int lg = lane >> 4;
  const int wr = w >> 1;
  const int wc = w & 1;

  __shared__ __bf16 At[2][32][LSTR];
  __shared__ __bf16 Bl[2][64][LSTR];
  __shared__ __bf16 Bw[2][64][LSTR];

  const int srow = tid >> 3;             // 0..31
  const int seg = tid & 7;               // 0..7
  const int ar = first + srow;
  const int sA = (ar < limit) ? perm[ar] : -1;
  const float* aP   = desc + (size_t)(sA < 0 ? 0 : sA) * DD + seg * 4;
  const int gc0 = cb * 64 + srow;
  const float* blP0 = layer1 + ((size_t)t * DD + gc0) * DD + seg * 4;
  const float* blP1 = blP0 + (size_t)32 * DD;
  const float* bwP0 = W + (size_t)gc0 * DD + seg * 4;
  const float* bwP1 = bwP0 + (size_t)32 * DD;

#define STAGE(buf, kb)                                                        \
  {                                                                           \
    float4 va = make_float4(0.f, 0.f, 0.f, 0.f);                              \
    if (sA >= 0) va = *reinterpret_cast<const float4*>(aP + (kb));            \
    *reinterpret_cast<bf16x4*>(&At[buf][srow][seg * 4]) = cvt4(va);           \
    *reinterpret_cast<bf16x4*>(&Bl[buf][srow][seg * 4]) =                     \
        cvt4(*reinterpret_cast<const float4*>(blP0 + (kb)));                  \
    *reinterpret_cast<bf16x4*>(&Bl[buf][srow + 32][seg * 4]) =                \
        cvt4(*reinterpret_cast<const float4*>(blP1 + (kb)));                  \
    *reinterpret_cast<bf16x4*>(&Bw[buf][srow][seg * 4]) =                     \
        cvt4(*reinterpret_cast<const float4*>(bwP0 + (kb)));                  \
    *reinterpret_cast<bf16x4*>(&Bw[buf][srow + 32][seg * 4]) =                \
        cvt4(*reinterpret_cast<const float4*>(bwP1 + (kb)));                  \
  }

  STAGE(0, 0)
  __syncthreads();

  f32x4 accL[2] = {{0.f,0.f,0.f,0.f},{0.f,0.f,0.f,0.f}};
  f32x4 accW[2] = {{0.f,0.f,0.f,0.f},{0.f,0.f,0.f,0.f}};
  int buf = 0;
#pragma unroll
  for (int kc = 0; kc < 8; ++kc) {
    if (kc < 7) STAGE(buf ^ 1, (kc + 1) * 32)
    bf16x8 af = *reinterpret_cast<const bf16x8*>(&At[buf][wr * 16 + l15][lg * 8]);
    bf16x8 b0 = *reinterpret_cast<const bf16x8*>(&Bl[buf][wc * 32 + l15][lg * 8]);
    bf16x8 b1 = *reinterpret_cast<const bf16x8*>(&Bl[buf][wc * 32 + 16 + l15][lg * 8]);
    bf16x8 w0 = *reinterpret_cast<const bf16x8*>(&Bw[buf][wc * 32 + l15][lg * 8]);
    bf16x8 w1 = *reinterpret_cast<const bf16x8*>(&Bw[buf][wc * 32 + 16 + l15][lg * 8]);
    accL[0] = __builtin_amdgcn_mfma_f32_16x16x32_bf16(af, b0, accL[0], 0, 0, 0);
    accL[1] = __builtin_amdgcn_mfma_f32_16x16x32_bf16(af, b1, accL[1], 0, 0, 0);
    accW[0] = __builtin_amdgcn_mfma_f32_16x16x32_bf16(af, w0, accW[0], 0, 0, 0);
    accW[1] = __builtin_amdgcn_mfma_f32_16x16x32_bf16(af, w1, accW[1], 0, 0, 0);
    __syncthreads();
    buf ^= 1;
  }
#undef STAGE

  const int orow = first + wr * 16 + l15;
  const int sOut = (orow < limit) ? perm[orow] : -1;
#pragma unroll
  for (int n = 0; n < 2; ++n) {
    const int col = cb * 64 + wc * 32 + n * 16 + l15;
    const float bv = bias[col];
#pragma unroll
    for (int i = 0; i < 4; ++i) {
      const int sv = __shfl(sOut, lg * 4 + i, 64);
      if (sv >= 0)
        __builtin_nontemporal_store(tanh_fast(accL[n][i]) + accW[n][i] + bv,
                                    out + (size_t)sv * DD + col);
    }
  }
}

extern "C" void kernel_launch(void* const* d_in, const int* in_sizes, int n_in,
                              void* d_out, int out_size, void* d_ws, size_t ws_size,
                              hipStream_t stream) {
  const int* bi       = (const int*)d_in[0];
  const float* desc   = (const float*)d_in[1];
  const float* layer1 = (const float*)d_in[2];
  const float* W      = (const float*)d_in[3];
  const float* bias   = (const float*)d_in[4];
  float* out = (float*)d_out;

  char* ws = (char*)d_ws;
  int* type_off = (int*)(ws);              // 65 ints   @ 0
  int* gtype    = (int*)(ws + 1024);       // 320 ints  @ 1 KB
  int* gfirst   = (int*)(ws + 4096);       // 320 ints  @ 4 KB
  int* perm     = (int*)(ws + 8192);       // 8192 ints @ 8 KB

  hipLaunchKernelGGL(build_perm32, dim3(1), dim3(1024), 0, stream,
                     bi, type_off, perm, gtype, gfirst);
  hipLaunchKernelGGL(gemm_tile, dim3(GM32 * 4), dim3(256), 0, stream,
                     desc, layer1, W, bias, type_off, perm, gtype, gfirst, out);
}